// Round 8
// baseline (244.146 us; speedup 1.0000x reference)
//
#include <hip/hip_runtime.h>
#include <math.h>

#define N_TOTAL 32768
#define N0 8192
#define N1 1024
#define KNB 8
#define C_IN 128
#define C_H 64
#define COS_T 0.999f
#define NEG_INF -1e30f
#define GRID 512
#define BLOCK 512

// sc1 agent-scope accessors: write-through to the Infinity-Cache coherence
// point. Producers of cross-block data STORE with these; consumers use PLAIN
// cached loads (safe: each buffer is written-once-then-read in this launch;
// dispatch start invalidates L2 — proven rounds 4-7).
__device__ __forceinline__ void stc(float* p, float v) {
    __hip_atomic_store(p, v, __ATOMIC_RELAXED, __HIP_MEMORY_SCOPE_AGENT);
}
__device__ __forceinline__ void stci(int* p, int v) {
    __hip_atomic_store(p, v, __ATOMIC_RELAXED, __HIP_MEMORY_SCOPE_AGENT);
}
__device__ __forceinline__ float ldc(const float* p) {
    return __hip_atomic_load(p, __ATOMIC_RELAXED, __HIP_MEMORY_SCOPE_AGENT);
}

struct MegaParams {
    const float* feat;
    const float* xyz;
    const float* wsS[3];
    const float* bsS[3];
    const float* dgWs[3];
    const float* dgWn[3];
    const float* dgB[3];
    const float* dgH[3];
    const float* dgHb[3];
    const int* nb0;
    const int* ind0;
    const int* isc[2];
    float* out;
    float* xs0[4];
    float* xs1[4];
    float* xs2[4];
    float* s0;
    float* sbr;
    float* xyz0;
    float* featT;
    int* anchorA;
    int* anchorB;
    int* indb1; int* nbb1;
    int* indb2; int* nbb2;
    unsigned* slot;    // [GRID] per-block arrival slots
    unsigned* flag;    // 8 replicated epoch lines (stride 16 words)
    int tr;
    int actCoh;
};

__global__ void __launch_bounds__(BLOCK, 4) mega_kernel(MegaParams P) {
    const int blk = blockIdx.x;
    const int tid = threadIdx.x;
    const int w = tid >> 6;      // wave id 0..7
    const int lane = tid & 63;   // channel

    __shared__ alignas(16) union {
        float tt[64][129];                                        // 33.0KB (transpose)
        struct { float wt[C_H * 132]; float col[16][C_IN]; } sp;  // 41.8KB (sphere)
        struct { float ws[C_H * 68]; float wn[C_H * 68];
                 float xw[16][C_H]; float aw[16][C_H]; } dg;      // 42.8KB (dgcn)
        struct { float sx[N1]; float sy[N1]; float sz[N1]; } tk;  // 12KB   (topk)
        float sc[N0];                                             // 32KB   (NMS)
    } u;
    __shared__ float rv[BLOCK];
    __shared__ int ri[BLOCK];
    __shared__ float psel[3];

    // Contention-free grid barrier (round-7 proven): per-block slot store,
    // block 0 polls slots in parallel, releases via 8 replicated flag lines.
    auto BAR = [&](int e) {
        asm volatile("s_waitcnt vmcnt(0)" ::: "memory");
        __syncthreads();
        if (blk == 0) {
            if (tid > 0 && tid < GRID) {
                while (__hip_atomic_load(&P.slot[tid], __ATOMIC_RELAXED,
                                         __HIP_MEMORY_SCOPE_AGENT) < (unsigned)e)
                    __builtin_amdgcn_s_sleep(1);
            }
            __syncthreads();
            if (tid < 8)
                __hip_atomic_store(&P.flag[tid * 16], (unsigned)e, __ATOMIC_RELAXED,
                                   __HIP_MEMORY_SCOPE_AGENT);
            __syncthreads();
        } else {
            if (tid == 0) {
                __hip_atomic_store(&P.slot[blk], (unsigned)e, __ATOMIC_RELAXED,
                                   __HIP_MEMORY_SCOPE_AGENT);
                while (__hip_atomic_load(&P.flag[(blk & 7) * 16], __ATOMIC_RELAXED,
                                         __HIP_MEMORY_SCOPE_AGENT) < (unsigned)e)
                    __builtin_amdgcn_s_sleep(2);
            }
            __syncthreads();
        }
    };

    // ---- sphere: 16 nodes (2/wave, interleaved; shared W reads) ----
    auto sphere = [&](int jb, const int* ind, const float* W, const float* bv,
                      float* xout) {
        __syncthreads();                          // union handoff
        const float4* W4 = (const float4*)W;
        for (int i4 = tid; i4 < C_H * C_IN / 4; i4 += BLOCK) {
            int c = i4 >> 5, kg = i4 & 31;        // granule stride 33: slot-distinct
            *(float4*)&u.sp.wt[c * 132 + kg * 4] = W4[i4];
        }
        __syncthreads();
        const int j0 = jb + w, j1 = jb + 8 + w;
        const int p0 = ind[j0], p1 = ind[j1];
        if (P.tr) {
            u.sp.col[2 * w + 0][lane]      = P.featT[(size_t)p0 * C_IN + lane];
            u.sp.col[2 * w + 0][lane + 64] = P.featT[(size_t)p0 * C_IN + lane + 64];
            u.sp.col[2 * w + 1][lane]      = P.featT[(size_t)p1 * C_IN + lane];
            u.sp.col[2 * w + 1][lane + 64] = P.featT[(size_t)p1 * C_IN + lane + 64];
        } else {
            u.sp.col[2 * w + 0][lane]      = P.feat[(size_t)lane * N_TOTAL + p0];
            u.sp.col[2 * w + 0][lane + 64] = P.feat[(size_t)(lane + 64) * N_TOTAL + p0];
            u.sp.col[2 * w + 1][lane]      = P.feat[(size_t)lane * N_TOTAL + p1];
            u.sp.col[2 * w + 1][lane + 64] = P.feat[(size_t)(lane + 64) * N_TOTAL + p1];
        }
        float acc0 = bv[lane], acc1 = acc0;
#pragma unroll
        for (int k4 = 0; k4 < C_IN / 4; ++k4) {
            float4 c0 = *(const float4*)&u.sp.col[2 * w + 0][k4 * 4];
            float4 c1 = *(const float4*)&u.sp.col[2 * w + 1][k4 * 4];
            float4 wv = *(const float4*)&u.sp.wt[lane * 132 + k4 * 4];
            acc0 += c0.x * wv.x; acc1 += c1.x * wv.x;
            acc0 += c0.y * wv.y; acc1 += c1.y * wv.y;
            acc0 += c0.z * wv.z; acc1 += c1.z * wv.z;
            acc0 += c0.w * wv.w; acc1 += c1.w * wv.w;
        }
        stc(&xout[(size_t)j0 * C_H + lane], acc0);
        stc(&xout[(size_t)j1 * C_H + lane], acc1);
    };

    // ---- one DGCN layer: 16 nodes (2/wave interleaved, hoisted loads,
    // ---- shared weight reads) ----
    auto dgcn = [&](int jb, const float* xin, const int* nbp,
                    const float* Wsl, const float* Wnl, const float* bias, int l,
                    float* xout, bool last, const float* head, const float* hb,
                    float* sdst, float* odst) {
        __syncthreads();                          // union handoff
        const float* Ws_ = Wsl + l * C_H * C_H;
        const float* Wn_ = Wnl + l * C_H * C_H;
        for (int i = tid; i < C_H * C_H; i += BLOCK) {
            int k = i >> 6, c = i & 63;           // coalesced read, transposed write
            u.dg.ws[c * 68 + k] = Ws_[i];
            u.dg.wn[c * 68 + k] = Wn_[i];
        }
        __syncthreads();
        const int j0 = jb + w, j1 = jb + 8 + w;
        float xv0, xv1, n0[KNB], n1[KNB];
        int q0[KNB], q1[KNB];
#pragma unroll
        for (int t = 0; t < KNB; ++t) q0[t] = nbp[j0 * KNB + t];
#pragma unroll
        for (int t = 0; t < KNB; ++t) q1[t] = nbp[j1 * KNB + t];
        if (!P.actCoh) {
            xv0 = xin[(size_t)j0 * C_H + lane];
            xv1 = xin[(size_t)j1 * C_H + lane];
#pragma unroll
            for (int t = 0; t < KNB; ++t) n0[t] = xin[(size_t)q0[t] * C_H + lane];
#pragma unroll
            for (int t = 0; t < KNB; ++t) n1[t] = xin[(size_t)q1[t] * C_H + lane];
        } else {
            xv0 = ldc(&xin[(size_t)j0 * C_H + lane]);
            xv1 = ldc(&xin[(size_t)j1 * C_H + lane]);
#pragma unroll
            for (int t = 0; t < KNB; ++t) n0[t] = ldc(&xin[(size_t)q0[t] * C_H + lane]);
#pragma unroll
            for (int t = 0; t < KNB; ++t) n1[t] = ldc(&xin[(size_t)q1[t] * C_H + lane]);
        }
        float a0 = 0.f, a1 = 0.f;
#pragma unroll
        for (int t = 0; t < KNB; ++t) a0 += n0[t];
#pragma unroll
        for (int t = 0; t < KNB; ++t) a1 += n1[t];
        u.dg.xw[2 * w + 0][lane] = xv0;
        u.dg.xw[2 * w + 1][lane] = xv1;
        u.dg.aw[2 * w + 0][lane] = a0 * (1.0f / KNB);
        u.dg.aw[2 * w + 1][lane] = a1 * (1.0f / KNB);
        // per-wave LDS slots: intra-wave ordering only
        float acc0 = bias[l * C_H + lane], acc1 = acc0;
#pragma unroll
        for (int k4 = 0; k4 < C_H / 4; ++k4) {
            float4 x0 = *(const float4*)&u.dg.xw[2 * w + 0][k4 * 4];
            float4 x1 = *(const float4*)&u.dg.xw[2 * w + 1][k4 * 4];
            float4 g0 = *(const float4*)&u.dg.aw[2 * w + 0][k4 * 4];
            float4 g1 = *(const float4*)&u.dg.aw[2 * w + 1][k4 * 4];
            float4 wsv = *(const float4*)&u.dg.ws[lane * 68 + k4 * 4];
            float4 wnv = *(const float4*)&u.dg.wn[lane * 68 + k4 * 4];
            acc0 += x0.x * wsv.x + g0.x * wnv.x;  acc1 += x1.x * wsv.x + g1.x * wnv.x;
            acc0 += x0.y * wsv.y + g0.y * wnv.y;  acc1 += x1.y * wsv.y + g1.y * wnv.y;
            acc0 += x0.z * wsv.z + g0.z * wnv.z;  acc1 += x1.z * wsv.z + g1.z * wnv.z;
            acc0 += x0.w * wsv.w + g0.w * wnv.w;  acc1 += x1.w * wsv.w + g1.w * wnv.w;
        }
        acc0 = fmaxf(acc0, 0.f);
        acc1 = fmaxf(acc1, 0.f);
        if (!last) {
            stc(&xout[(size_t)j0 * C_H + lane], acc0);
            stc(&xout[(size_t)j1 * C_H + lane], acc1);
        } else {
            float v0 = acc0 * head[lane];
            float v1 = acc1 * head[lane];
#pragma unroll
            for (int off = 32; off > 0; off >>= 1) {
                v0 += __shfl_down(v0, off, 64);
                v1 += __shfl_down(v1, off, 64);
            }
            if (lane == 0) {
                float s0v = v0 + hb[0], s1v = v1 + hb[0];
                if (sdst) { stc(&sdst[j0], s0v); stc(&sdst[j1], s1v); }
                odst[j0] = 1.f / (1.f + expf(-s0v));   // plain; flushed at kernel end
                odst[j1] = 1.f / (1.f + expf(-s1v));
            }
        }
    };

    // ---- fused gather + per-row stable top-8; 16 rows/block (active blocks) ----
    auto topk = [&](const int* isc, const int* anc, int* indb, int* nbb,
                    int br, int sl) {
        __syncthreads();                          // union handoff
        const int a = anc[br];                    // plain (fresh line)
        const int* row = isc + (size_t)a * N1;
#pragma unroll
        for (int mm = 0; mm < 2; ++mm) {
            int m = mm * BLOCK + tid;
            int pp = row[m];
            u.tk.sx[m] = P.xyz[pp * 3 + 0];
            u.tk.sy[m] = P.xyz[pp * 3 + 1];
            u.tk.sz[m] = P.xyz[pp * 3 + 2];
        }
        if (tid < 16) {
            int r = sl * 16 + tid;
            stci(&indb[br * N1 + r], row[r]);
        }
        __syncthreads();
#pragma unroll
        for (int rr = 0; rr < 2; ++rr) {
            const int r = sl * 16 + rr * 8 + w;   // branch-local row
            const int grow = br * N1 + r;
            float rx = u.tk.sx[r], ry = u.tk.sy[r], rz = u.tk.sz[r];
            unsigned long long k[16];
#pragma unroll
            for (int t = 0; t < 16; ++t) {
                int m = t * 64 + lane;            // lane-consecutive: conflict-free
                float v = fabsf(rx * u.tk.sx[m] + ry * u.tk.sy[m] + rz * u.tk.sz[m]);
                k[t] = ((unsigned long long)__float_as_uint(v) << 32)
                     | (unsigned int)(0xFFFFFFFFu - (unsigned int)m);
            }
#pragma unroll
            for (int pass = 0; pass < KNB; ++pass) {
                unsigned long long lm = k[0];
#pragma unroll
                for (int t = 1; t < 16; ++t) lm = (k[t] > lm) ? k[t] : lm;
#pragma unroll
                for (int off = 1; off < 64; off <<= 1) {
                    unsigned long long o = __shfl_xor(lm, off, 64);
                    lm = (o > lm) ? o : lm;
                }
                if (lane == 0) {
                    int idx = (int)(0xFFFFFFFFu - (unsigned int)(lm & 0xFFFFFFFFull));
                    stci(&nbb[grow * KNB + pass], br * N1 + idx);
                }
#pragma unroll
                for (int t = 0; t < 16; ++t) if (k[t] == lm) k[t] = 0;
            }
        }
        // publish indb/nbb so this block's own plain reads see them
        asm volatile("s_waitcnt vmcnt(0)" ::: "memory");
        __syncthreads();
    };

    // ===== epoch 1: feat transpose (64 cols/block) + xyz0 gather =====
    if (P.tr) {
        const int g0 = blk * 64;
        const int col = tid & 63, rowH = tid >> 6;
        for (int c0 = 0; c0 < C_IN; c0 += 8) {
            int c = c0 + rowH;
            u.tt[col][c] = P.feat[(size_t)c * N_TOTAL + g0 + col];    // coalesced
        }
        __syncthreads();
        for (int i = tid; i < 64 * C_IN; i += BLOCK) {
            int cc = i >> 7, c = i & 127;
            stc(&P.featT[(size_t)(g0 + cc) * C_IN + c], u.tt[cc][c]); // coalesced
        }
    }
    if (tid < 16) {
        int j = blk * 16 + tid;
        int p = P.ind0[j];
        stc(&P.xyz0[j * 3 + 0], P.xyz[p * 3 + 0]);
        stc(&P.xyz0[j * 3 + 1], P.xyz[p * 3 + 1]);
        stc(&P.xyz0[j * 3 + 2], P.xyz[p * 3 + 2]);
    }
    BAR(1);

    // ===== stage 0 (16 nodes/block, all 512 blocks) =====
    const int jb0 = blk * 16;
    sphere(jb0, P.ind0, P.wsS[0], P.bsS[0], P.xs0[0]);
    BAR(2);
    dgcn(jb0, P.xs0[0], P.nb0, P.dgWs[0], P.dgWn[0], P.dgB[0], 0, P.xs0[1], false, nullptr, nullptr, nullptr, nullptr);
    BAR(3);
    dgcn(jb0, P.xs0[1], P.nb0, P.dgWs[0], P.dgWn[0], P.dgB[0], 1, P.xs0[2], false, nullptr, nullptr, nullptr, nullptr);
    BAR(4);
    dgcn(jb0, P.xs0[2], P.nb0, P.dgWs[0], P.dgWn[0], P.dgB[0], 2, P.xs0[3], false, nullptr, nullptr, nullptr, nullptr);
    BAR(5);
    dgcn(jb0, P.xs0[3], P.nb0, P.dgWs[0], P.dgWn[0], P.dgB[0], 3, nullptr, true,
         P.dgH[0], P.dgHb[0], P.s0, P.out);
    BAR(6);

    // ===== NMS (block 0 only) =====
    if (blk == 0) {
        for (int jj = tid; jj < N0; jj += BLOCK) u.sc[jj] = P.s0[jj];
        __syncthreads();
        for (int it = 0; it < 3; ++it) {
            float bv = -INFINITY; int bi = 0x7fffffff;
            for (int jj = tid; jj < N0; jj += BLOCK) {
                float v = u.sc[jj];
                if (v > bv) { bv = v; bi = jj; }   // strided ascending: first max kept
            }
            rv[tid] = bv; ri[tid] = bi;
            __syncthreads();
            for (int sft = BLOCK / 2; sft > 0; sft >>= 1) {
                if (tid < sft) {
                    float v2 = rv[tid + sft]; int i2 = ri[tid + sft];
                    if (v2 > rv[tid] || (v2 == rv[tid] && i2 < ri[tid])) {
                        rv[tid] = v2; ri[tid] = i2;
                    }
                }
                __syncthreads();
            }
            int sel = ri[0];
            if (tid == 0) {
                stci(&P.anchorA[it], P.ind0[sel]);
                psel[0] = P.xyz0[sel * 3 + 0];
                psel[1] = P.xyz0[sel * 3 + 1];
                psel[2] = P.xyz0[sel * 3 + 2];
            }
            __syncthreads();
            float px = psel[0], py = psel[1], pz = psel[2];
            for (int jj = tid; jj < N0; jj += BLOCK) {
                float d = fabsf(P.xyz0[jj * 3 + 0] * px + P.xyz0[jj * 3 + 1] * py
                              + P.xyz0[jj * 3 + 2] * pz);
                if (d >= COS_T) u.sc[jj] = NEG_INF;
            }
            __syncthreads();
        }
    }
    BAR(7);

    // ===== stages 1 & 2: branch<->XCD affinity =====
    // Active blocks: blk%8 in {0,1,2}; branch = blk%8; 64 blocks/branch x 16
    // nodes. Empirically blockIdx round-robins XCDs, so one branch's 256KB
    // activation set stays in ONE XCD's L2 (perf heuristic only; correctness
    // holds regardless of mapping).
    const int br = blk & 7;
    const int sl = blk >> 3;
    const bool act12 = (br < 3);
    const int jb12 = br * N1 + sl * 16;

    for (int st = 1; st <= 2; ++st) {
        float* const* xb = (st == 1) ? P.xs1 : P.xs2;
        int* indb = (st == 1) ? P.indb1 : P.indb2;
        int* nbb  = (st == 1) ? P.nbb1  : P.nbb2;
        const int* anc = (st == 1) ? P.anchorA : P.anchorB;
        const int ep = (st == 1) ? 7 : 13;

        if (act12) {
            topk(P.isc[st - 1], anc, indb, nbb, br, sl);
            sphere(jb12, indb, P.wsS[st], P.bsS[st], xb[0]);
        }
        BAR(ep + 1);
        if (act12) dgcn(jb12, xb[0], nbb, P.dgWs[st], P.dgWn[st], P.dgB[st], 0, xb[1], false, nullptr, nullptr, nullptr, nullptr);
        BAR(ep + 2);
        if (act12) dgcn(jb12, xb[1], nbb, P.dgWs[st], P.dgWn[st], P.dgB[st], 1, xb[2], false, nullptr, nullptr, nullptr, nullptr);
        BAR(ep + 3);
        if (act12) dgcn(jb12, xb[2], nbb, P.dgWs[st], P.dgWn[st], P.dgB[st], 2, xb[3], false, nullptr, nullptr, nullptr, nullptr);
        BAR(ep + 4);
        if (act12) dgcn(jb12, xb[3], nbb, P.dgWs[st], P.dgWn[st], P.dgB[st], 3, nullptr, true,
                        P.dgH[st], P.dgHb[st], (st == 1) ? P.sbr : nullptr,
                        P.out + N0 + (st - 1) * 3 * N1);
        if (st == 1) {
            BAR(12);
            if (blk < 3) {    // per-branch argmax over sbr (plain, fresh)
                float bv = -INFINITY; int bi = 0x7fffffff;
                for (int m = tid; m < N1; m += BLOCK) {
                    float v = P.sbr[blk * N1 + m];
                    if (v > bv) { bv = v; bi = m; }   // ascending: first max kept
                }
                rv[tid] = bv; ri[tid] = bi;
                __syncthreads();
                for (int sft = BLOCK / 2; sft > 0; sft >>= 1) {
                    if (tid < sft) {
                        float v2 = rv[tid + sft]; int i2 = ri[tid + sft];
                        if (v2 > rv[tid] || (v2 == rv[tid] && i2 < ri[tid])) {
                            rv[tid] = v2; ri[tid] = i2;
                        }
                    }
                    __syncthreads();
                }
                if (tid == 0) stci(&P.anchorB[blk], P.indb1[blk * N1 + ri[0]]);
            }
            BAR(13);
        }
    }
}

extern "C" void kernel_launch(void* const* d_in, const int* in_sizes, int n_in,
                              void* d_out, int out_size, void* d_ws, size_t ws_size,
                              hipStream_t stream) {
    MegaParams hp;
    hp.feat = (const float*)d_in[0];
    hp.xyz  = (const float*)d_in[1];
    hp.wsS[0] = (const float*)d_in[2];  hp.bsS[0] = (const float*)d_in[3];
    hp.wsS[1] = (const float*)d_in[4];  hp.bsS[1] = (const float*)d_in[5];
    hp.wsS[2] = (const float*)d_in[6];  hp.bsS[2] = (const float*)d_in[7];
    hp.dgWs[0] = (const float*)d_in[8];  hp.dgWn[0] = (const float*)d_in[9];
    hp.dgB[0]  = (const float*)d_in[10]; hp.dgH[0]  = (const float*)d_in[11];
    hp.dgHb[0] = (const float*)d_in[12];
    hp.dgWs[1] = (const float*)d_in[13]; hp.dgWn[1] = (const float*)d_in[14];
    hp.dgB[1]  = (const float*)d_in[15]; hp.dgH[1]  = (const float*)d_in[16];
    hp.dgHb[1] = (const float*)d_in[17];
    hp.dgWs[2] = (const float*)d_in[18]; hp.dgWn[2] = (const float*)d_in[19];
    hp.dgB[2]  = (const float*)d_in[20]; hp.dgH[2]  = (const float*)d_in[21];
    hp.dgHb[2] = (const float*)d_in[22];
    const int* edge0 = (const int*)d_in[23];
    hp.nb0  = edge0 + N0 * KNB;
    hp.ind0 = (const int*)d_in[24];
    hp.isc[0] = (const int*)d_in[25];
    hp.isc[1] = (const int*)d_in[26];
    hp.out = (float*)d_out;

    float* f = (float*)d_ws;
    size_t o = 0;
    auto takeF = [&](size_t n) { float* p = f + o; o += n; return p; };

    hp.s0   = takeF(N0);
    hp.sbr  = takeF(3 * N1);
    hp.xyz0 = takeF((size_t)N0 * 3);
    o = (o + 63) & ~(size_t)63;
    hp.anchorA = (int*)takeF(64);
    hp.anchorB = (int*)takeF(64);
    hp.indb1 = (int*)takeF(3 * N1);
    hp.nbb1  = (int*)takeF(3 * N1 * KNB);
    hp.indb2 = (int*)takeF(3 * N1);
    hp.nbb2  = (int*)takeF(3 * N1 * KNB);
    o = (o + 63) & ~(size_t)63;
    hp.slot = (unsigned*)takeF(GRID);
    hp.flag = (unsigned*)takeF(8 * 16);
    unsigned* ctrBase = hp.slot;

    size_t needFast = (o + 4 * (size_t)N0 * C_H + 8 * (size_t)(3 * N1) * C_H) * sizeof(float);
    if (ws_size >= needFast) {
        hp.actCoh = 0;
        for (int i = 0; i < 4; ++i) hp.xs0[i] = takeF((size_t)N0 * C_H);
        for (int i = 0; i < 4; ++i) hp.xs1[i] = takeF((size_t)(3 * N1) * C_H);
        for (int i = 0; i < 4; ++i) hp.xs2[i] = takeF((size_t)(3 * N1) * C_H);
    } else {
        hp.actCoh = 1;
        float* xA = takeF((size_t)N0 * C_H);
        float* xB = takeF((size_t)N0 * C_H);
        for (int i = 0; i < 4; ++i) {
            hp.xs0[i] = (i & 1) ? xB : xA;
            hp.xs1[i] = (i & 1) ? xB : xA;
            hp.xs2[i] = (i & 1) ? xB : xA;
        }
    }

    size_t needTr = (o + (size_t)N_TOTAL * C_IN) * sizeof(float);
    if (ws_size >= needTr) {
        hp.tr = 1;
        hp.featT = takeF((size_t)N_TOTAL * C_IN);
    } else {
        hp.tr = 0;
        hp.featT = nullptr;
    }

    hipMemsetAsync((void*)ctrBase, 0, (GRID + 8 * 16) * sizeof(unsigned), stream);
    mega_kernel<<<dim3(GRID), dim3(BLOCK), 0, stream>>>(hp);
}

// Round 9
// 173.780 us; speedup vs baseline: 1.4049x; 1.4049x over previous
//
#include <hip/hip_runtime.h>
#include <math.h>

#define N_TOTAL 32768
#define N0 8192
#define N1 1024
#define KNB 8
#define C_IN 128
#define C_H 64
#define COS_T 0.999f
#define NEG_INF -1e30f
#define GRID 512
#define BLOCK 512
#define NACT 384      // blocks that stay alive after stage 0
#define SLOT_DONE 0x7fffffffu

// sc1 agent-scope accessors: write-through to the Infinity-Cache coherence
// point. Producers of cross-block data STORE with these; consumers use PLAIN
// cached loads (safe: each buffer is written-once-then-read in this launch;
// dispatch start invalidates L2 — proven rounds 4-7).
__device__ __forceinline__ void stc(float* p, float v) {
    __hip_atomic_store(p, v, __ATOMIC_RELAXED, __HIP_MEMORY_SCOPE_AGENT);
}
__device__ __forceinline__ void stci(int* p, int v) {
    __hip_atomic_store(p, v, __ATOMIC_RELAXED, __HIP_MEMORY_SCOPE_AGENT);
}
__device__ __forceinline__ float ldc(const float* p) {
    return __hip_atomic_load(p, __ATOMIC_RELAXED, __HIP_MEMORY_SCOPE_AGENT);
}

struct MegaParams {
    const float* feat;
    const float* xyz;
    const float* wsS[3];
    const float* bsS[3];
    const float* dgWs[3];
    const float* dgWn[3];
    const float* dgB[3];
    const float* dgH[3];
    const float* dgHb[3];
    const int* nb0;
    const int* ind0;
    const int* isc[2];
    float* out;
    float* xs0[4];
    float* xs1[4];
    float* xs2[4];
    float* s0;
    float* sbr;
    float* xyz0;
    float* featT;
    int* anchorA;
    int* anchorB;
    int* indb1; int* nbb1;
    int* indb2; int* nbb2;
    unsigned* slot;    // [GRID] per-block arrival slots
    unsigned* flag;    // 8 replicated epoch lines (stride 16 words)
    int tr;
    int actCoh;
};

__global__ void __launch_bounds__(BLOCK, 4) mega_kernel(MegaParams P) {
    const int blk = blockIdx.x;
    const int tid = threadIdx.x;
    const int w = tid >> 6;      // wave id 0..7
    const int lane = tid & 63;   // channel

    __shared__ alignas(16) union {
        float tt[64][129];                                        // 33.0KB (transpose)
        struct { float wt[C_H * 132]; float col[16][C_IN]; } sp;  // 41.8KB (sphere)
        struct { float ws[C_H * 68]; float wn[C_H * 68];
                 float xw[16][C_H]; float aw[16][C_H]; } dg;      // 42.0KB (dgcn)
        struct { float sx[N1]; float sy[N1]; float sz[N1]; } tk;  // 12KB   (topk)
        float sc[N0];                                             // 32KB   (NMS)
    } u;
    __shared__ float rv[BLOCK];
    __shared__ int ri[BLOCK];
    __shared__ float psel[3];

    // Contention-free grid barrier (round-7 proven): per-block slot store,
    // block 0 polls slots in parallel, releases via 8 replicated flag lines.
    auto BAR = [&](int e) {
        asm volatile("s_waitcnt vmcnt(0)" ::: "memory");
        __syncthreads();
        if (blk == 0) {
            if (tid > 0 && tid < GRID) {
                while (__hip_atomic_load(&P.slot[tid], __ATOMIC_RELAXED,
                                         __HIP_MEMORY_SCOPE_AGENT) < (unsigned)e)
                    __builtin_amdgcn_s_sleep(1);
            }
            __syncthreads();
            if (tid < 8)
                __hip_atomic_store(&P.flag[tid * 16], (unsigned)e, __ATOMIC_RELAXED,
                                   __HIP_MEMORY_SCOPE_AGENT);
            __syncthreads();
        } else {
            if (tid == 0) {
                __hip_atomic_store(&P.slot[blk], (unsigned)e, __ATOMIC_RELAXED,
                                   __HIP_MEMORY_SCOPE_AGENT);
                while (__hip_atomic_load(&P.flag[(blk & 7) * 16], __ATOMIC_RELAXED,
                                         __HIP_MEMORY_SCOPE_AGENT) < (unsigned)e)
                    __builtin_amdgcn_s_sleep(2);
            }
            __syncthreads();
        }
    };

    // ---- sphere: npb nodes/block; W^T staged wt[c*132+k] (b128 writes/reads).
    // ---- npb==16: 2 nodes/wave interleaved (shared W reads); npb==8: 1/wave.
    auto sphere = [&](int npb, int jb, const int* ind, const float* W,
                      const float* bv, float* xout) {
        __syncthreads();                          // union handoff
        const float4* W4 = (const float4*)W;
        for (int i4 = tid; i4 < C_H * C_IN / 4; i4 += BLOCK) {
            int c = i4 >> 5, kg = i4 & 31;        // granule stride 33: slot-distinct
            *(float4*)&u.sp.wt[c * 132 + kg * 4] = W4[i4];
        }
        __syncthreads();
        if (npb == 16) {
            const int j0 = jb + w, j1 = jb + 8 + w;
            const int p0 = ind[j0], p1 = ind[j1];
            if (P.tr) {
                u.sp.col[2 * w + 0][lane]      = P.featT[(size_t)p0 * C_IN + lane];
                u.sp.col[2 * w + 0][lane + 64] = P.featT[(size_t)p0 * C_IN + lane + 64];
                u.sp.col[2 * w + 1][lane]      = P.featT[(size_t)p1 * C_IN + lane];
                u.sp.col[2 * w + 1][lane + 64] = P.featT[(size_t)p1 * C_IN + lane + 64];
            } else {
                u.sp.col[2 * w + 0][lane]      = P.feat[(size_t)lane * N_TOTAL + p0];
                u.sp.col[2 * w + 0][lane + 64] = P.feat[(size_t)(lane + 64) * N_TOTAL + p0];
                u.sp.col[2 * w + 1][lane]      = P.feat[(size_t)lane * N_TOTAL + p1];
                u.sp.col[2 * w + 1][lane + 64] = P.feat[(size_t)(lane + 64) * N_TOTAL + p1];
            }
            float acc0 = bv[lane], acc1 = acc0;
#pragma unroll
            for (int k4 = 0; k4 < C_IN / 4; ++k4) {
                float4 c0 = *(const float4*)&u.sp.col[2 * w + 0][k4 * 4];
                float4 c1 = *(const float4*)&u.sp.col[2 * w + 1][k4 * 4];
                float4 wv = *(const float4*)&u.sp.wt[lane * 132 + k4 * 4];
                acc0 += c0.x * wv.x; acc1 += c1.x * wv.x;
                acc0 += c0.y * wv.y; acc1 += c1.y * wv.y;
                acc0 += c0.z * wv.z; acc1 += c1.z * wv.z;
                acc0 += c0.w * wv.w; acc1 += c1.w * wv.w;
            }
            stc(&xout[(size_t)j0 * C_H + lane], acc0);
            stc(&xout[(size_t)j1 * C_H + lane], acc1);
        } else {
            const int j = jb + w;
            const int p = ind[j];
            if (P.tr) {
                u.sp.col[w][lane]      = P.featT[(size_t)p * C_IN + lane];
                u.sp.col[w][lane + 64] = P.featT[(size_t)p * C_IN + lane + 64];
            } else {
                u.sp.col[w][lane]      = P.feat[(size_t)lane * N_TOTAL + p];
                u.sp.col[w][lane + 64] = P.feat[(size_t)(lane + 64) * N_TOTAL + p];
            }
            float acc = bv[lane];
#pragma unroll
            for (int k4 = 0; k4 < C_IN / 4; ++k4) {
                float4 cv = *(const float4*)&u.sp.col[w][k4 * 4];
                float4 wv = *(const float4*)&u.sp.wt[lane * 132 + k4 * 4];
                acc += cv.x * wv.x;
                acc += cv.y * wv.y;
                acc += cv.z * wv.z;
                acc += cv.w * wv.w;
            }
            stc(&xout[(size_t)j * C_H + lane], acc);
        }
    };

    // ---- one DGCN layer; weights staged c-major ws[c*68+k] via b128 writes
    // ---- (8 coalesced global loads -> 2 ds_write_b128: 8x fewer conflicted
    // ---- stores than scalar transposing writes). npb==16: 2 nodes/wave.
    auto dgcn = [&](int npb, int jb, const float* xin, const int* nbp,
                    const float* Wsl, const float* Wnl, const float* bias, int l,
                    float* xout, bool last, const float* head, const float* hb,
                    float* sdst, float* odst) {
        __syncthreads();                          // union handoff
        const float* Ws_ = Wsl + l * C_H * C_H;
        const float* Wn_ = Wnl + l * C_H * C_H;
        {
            const int c = tid & 63;
            const int k0 = (tid >> 6) * 8;        // 512 threads cover 64c x 8 kgrp
            float v0, v1, v2, v3, v4, v5, v6, v7;
            v0 = Ws_[(k0 + 0) * C_H + c]; v1 = Ws_[(k0 + 1) * C_H + c];
            v2 = Ws_[(k0 + 2) * C_H + c]; v3 = Ws_[(k0 + 3) * C_H + c];
            v4 = Ws_[(k0 + 4) * C_H + c]; v5 = Ws_[(k0 + 5) * C_H + c];
            v6 = Ws_[(k0 + 6) * C_H + c]; v7 = Ws_[(k0 + 7) * C_H + c];
            *(float4*)&u.dg.ws[c * 68 + k0]     = make_float4(v0, v1, v2, v3);
            *(float4*)&u.dg.ws[c * 68 + k0 + 4] = make_float4(v4, v5, v6, v7);
            v0 = Wn_[(k0 + 0) * C_H + c]; v1 = Wn_[(k0 + 1) * C_H + c];
            v2 = Wn_[(k0 + 2) * C_H + c]; v3 = Wn_[(k0 + 3) * C_H + c];
            v4 = Wn_[(k0 + 4) * C_H + c]; v5 = Wn_[(k0 + 5) * C_H + c];
            v6 = Wn_[(k0 + 6) * C_H + c]; v7 = Wn_[(k0 + 7) * C_H + c];
            *(float4*)&u.dg.wn[c * 68 + k0]     = make_float4(v0, v1, v2, v3);
            *(float4*)&u.dg.wn[c * 68 + k0 + 4] = make_float4(v4, v5, v6, v7);
        }
        __syncthreads();
        if (npb == 16) {
            const int j0 = jb + w, j1 = jb + 8 + w;
            int q0[KNB], q1[KNB];
            float n0[KNB], n1[KNB];
#pragma unroll
            for (int t = 0; t < KNB; ++t) q0[t] = nbp[j0 * KNB + t];
#pragma unroll
            for (int t = 0; t < KNB; ++t) q1[t] = nbp[j1 * KNB + t];
            float xv0, xv1;
            if (!P.actCoh) {
                xv0 = xin[(size_t)j0 * C_H + lane];
                xv1 = xin[(size_t)j1 * C_H + lane];
#pragma unroll
                for (int t = 0; t < KNB; ++t) n0[t] = xin[(size_t)q0[t] * C_H + lane];
#pragma unroll
                for (int t = 0; t < KNB; ++t) n1[t] = xin[(size_t)q1[t] * C_H + lane];
            } else {
                xv0 = ldc(&xin[(size_t)j0 * C_H + lane]);
                xv1 = ldc(&xin[(size_t)j1 * C_H + lane]);
#pragma unroll
                for (int t = 0; t < KNB; ++t) n0[t] = ldc(&xin[(size_t)q0[t] * C_H + lane]);
#pragma unroll
                for (int t = 0; t < KNB; ++t) n1[t] = ldc(&xin[(size_t)q1[t] * C_H + lane]);
            }
            float a0 = 0.f, a1 = 0.f;
#pragma unroll
            for (int t = 0; t < KNB; ++t) a0 += n0[t];
#pragma unroll
            for (int t = 0; t < KNB; ++t) a1 += n1[t];
            u.dg.xw[2 * w + 0][lane] = xv0;
            u.dg.xw[2 * w + 1][lane] = xv1;
            u.dg.aw[2 * w + 0][lane] = a0 * (1.0f / KNB);
            u.dg.aw[2 * w + 1][lane] = a1 * (1.0f / KNB);
            // per-wave LDS slots: intra-wave ordering only
            float acc0 = bias[l * C_H + lane], acc1 = acc0;
#pragma unroll
            for (int k4 = 0; k4 < C_H / 4; ++k4) {
                float4 x0 = *(const float4*)&u.dg.xw[2 * w + 0][k4 * 4];
                float4 x1 = *(const float4*)&u.dg.xw[2 * w + 1][k4 * 4];
                float4 g0 = *(const float4*)&u.dg.aw[2 * w + 0][k4 * 4];
                float4 g1 = *(const float4*)&u.dg.aw[2 * w + 1][k4 * 4];
                float4 wsv = *(const float4*)&u.dg.ws[lane * 68 + k4 * 4];
                float4 wnv = *(const float4*)&u.dg.wn[lane * 68 + k4 * 4];
                acc0 += x0.x * wsv.x + g0.x * wnv.x;  acc1 += x1.x * wsv.x + g1.x * wnv.x;
                acc0 += x0.y * wsv.y + g0.y * wnv.y;  acc1 += x1.y * wsv.y + g1.y * wnv.y;
                acc0 += x0.z * wsv.z + g0.z * wnv.z;  acc1 += x1.z * wsv.z + g1.z * wnv.z;
                acc0 += x0.w * wsv.w + g0.w * wnv.w;  acc1 += x1.w * wsv.w + g1.w * wnv.w;
            }
            acc0 = fmaxf(acc0, 0.f);
            acc1 = fmaxf(acc1, 0.f);
            if (!last) {
                stc(&xout[(size_t)j0 * C_H + lane], acc0);
                stc(&xout[(size_t)j1 * C_H + lane], acc1);
            } else {
                float v0 = acc0 * head[lane];
                float v1 = acc1 * head[lane];
#pragma unroll
                for (int off = 32; off > 0; off >>= 1) {
                    v0 += __shfl_down(v0, off, 64);
                    v1 += __shfl_down(v1, off, 64);
                }
                if (lane == 0) {
                    float s0v = v0 + hb[0], s1v = v1 + hb[0];
                    if (sdst) { stc(&sdst[j0], s0v); stc(&sdst[j1], s1v); }
                    odst[j0] = 1.f / (1.f + expf(-s0v));   // plain; flushed at end
                    odst[j1] = 1.f / (1.f + expf(-s1v));
                }
            }
        } else {
            const int j = jb + w;
            float xv, a = 0.f;
            if (!P.actCoh) {
                xv = xin[(size_t)j * C_H + lane];
#pragma unroll
                for (int t = 0; t < KNB; ++t) {
                    int q = nbp[j * KNB + t];
                    a += xin[(size_t)q * C_H + lane];
                }
            } else {
                xv = ldc(&xin[(size_t)j * C_H + lane]);
#pragma unroll
                for (int t = 0; t < KNB; ++t) {
                    int q = nbp[j * KNB + t];
                    a += ldc(&xin[(size_t)q * C_H + lane]);
                }
            }
            u.dg.xw[w][lane] = xv;
            u.dg.aw[w][lane] = a * (1.0f / KNB);
            float acc = bias[l * C_H + lane];
#pragma unroll
            for (int k4 = 0; k4 < C_H / 4; ++k4) {
                float4 xv4 = *(const float4*)&u.dg.xw[w][k4 * 4];
                float4 av4 = *(const float4*)&u.dg.aw[w][k4 * 4];
                float4 wsv = *(const float4*)&u.dg.ws[lane * 68 + k4 * 4];
                float4 wnv = *(const float4*)&u.dg.wn[lane * 68 + k4 * 4];
                acc += xv4.x * wsv.x + av4.x * wnv.x;
                acc += xv4.y * wsv.y + av4.y * wnv.y;
                acc += xv4.z * wsv.z + av4.z * wnv.z;
                acc += xv4.w * wsv.w + av4.w * wnv.w;
            }
            acc = fmaxf(acc, 0.f);
            if (!last) {
                stc(&xout[(size_t)j * C_H + lane], acc);
            } else {
                float v = acc * head[lane];
#pragma unroll
                for (int off = 32; off > 0; off >>= 1) v += __shfl_down(v, off, 64);
                if (lane == 0) {
                    float s = v + hb[0];
                    if (sdst) stc(&sdst[j], s);
                    odst[j] = 1.f / (1.f + expf(-s));
                }
            }
        }
    };

    // ---- fused gather + per-row stable top-8; 8 rows/block (NACT blocks) ----
    auto topk = [&](const int* isc, const int* anc, int* indb, int* nbb) {
        __syncthreads();                          // union handoff
        const int b = blk >> 7;                   // branch (128 blocks per branch)
        const int a = anc[b];                     // plain (fresh line)
        const int* row = isc + (size_t)a * N1;
#pragma unroll
        for (int mm = 0; mm < 2; ++mm) {
            int m = mm * BLOCK + tid;
            int pp = row[m];
            u.tk.sx[m] = P.xyz[pp * 3 + 0];
            u.tk.sy[m] = P.xyz[pp * 3 + 1];
            u.tk.sz[m] = P.xyz[pp * 3 + 2];
        }
        if (tid < 8) {
            int grow = blk * 8 + tid;
            stci(&indb[grow], row[grow & (N1 - 1)]);
        }
        __syncthreads();
        {
            const int grow = blk * 8 + w;         // one row per wave
            const int r = grow & (N1 - 1);
            float rx = u.tk.sx[r], ry = u.tk.sy[r], rz = u.tk.sz[r];
            unsigned long long k[16];
#pragma unroll
            for (int t = 0; t < 16; ++t) {
                int m = t * 64 + lane;            // lane-consecutive: conflict-free
                float v = fabsf(rx * u.tk.sx[m] + ry * u.tk.sy[m] + rz * u.tk.sz[m]);
                k[t] = ((unsigned long long)__float_as_uint(v) << 32)
                     | (unsigned int)(0xFFFFFFFFu - (unsigned int)m);
            }
#pragma unroll
            for (int pass = 0; pass < KNB; ++pass) {
                unsigned long long lm = k[0];
#pragma unroll
                for (int t = 1; t < 16; ++t) lm = (k[t] > lm) ? k[t] : lm;
#pragma unroll
                for (int off = 1; off < 64; off <<= 1) {
                    unsigned long long o = __shfl_xor(lm, off, 64);
                    lm = (o > lm) ? o : lm;
                }
                if (lane == 0) {
                    int idx = (int)(0xFFFFFFFFu - (unsigned int)(lm & 0xFFFFFFFFull));
                    stci(&nbb[grow * KNB + pass], b * N1 + idx);
                }
#pragma unroll
                for (int t = 0; t < 16; ++t) if (k[t] == lm) k[t] = 0;
            }
        }
        // publish indb/nbb so this block's own plain reads see them
        asm volatile("s_waitcnt vmcnt(0)" ::: "memory");
        __syncthreads();
    };

    // ===== epoch 1: feat transpose (64 cols/block) + xyz0 gather =====
    if (P.tr) {
        const int g0 = blk * 64;
        const int col = tid & 63, rowH = tid >> 6;
        for (int c0 = 0; c0 < C_IN; c0 += 8) {
            int c = c0 + rowH;
            u.tt[col][c] = P.feat[(size_t)c * N_TOTAL + g0 + col];    // coalesced
        }
        __syncthreads();
        for (int i = tid; i < 64 * C_IN; i += BLOCK) {
            int cc = i >> 7, c = i & 127;
            stc(&P.featT[(size_t)(g0 + cc) * C_IN + c], u.tt[cc][c]); // coalesced
        }
    }
    if (tid < 16) {
        int j = blk * 16 + tid;
        int p = P.ind0[j];
        stc(&P.xyz0[j * 3 + 0], P.xyz[p * 3 + 0]);
        stc(&P.xyz0[j * 3 + 1], P.xyz[p * 3 + 1]);
        stc(&P.xyz0[j * 3 + 2], P.xyz[p * 3 + 2]);
    }
    BAR(1);

    // ===== stage 0 (16 nodes/block, all 512 blocks; 2 nodes/wave) =====
    const int jb0 = blk * 16;
    sphere(16, jb0, P.ind0, P.wsS[0], P.bsS[0], P.xs0[0]);
    BAR(2);
    dgcn(16, jb0, P.xs0[0], P.nb0, P.dgWs[0], P.dgWn[0], P.dgB[0], 0, P.xs0[1], false, nullptr, nullptr, nullptr, nullptr);
    BAR(3);
    dgcn(16, jb0, P.xs0[1], P.nb0, P.dgWs[0], P.dgWn[0], P.dgB[0], 1, P.xs0[2], false, nullptr, nullptr, nullptr, nullptr);
    BAR(4);
    dgcn(16, jb0, P.xs0[2], P.nb0, P.dgWs[0], P.dgWn[0], P.dgB[0], 2, P.xs0[3], false, nullptr, nullptr, nullptr, nullptr);
    BAR(5);
    dgcn(16, jb0, P.xs0[3], P.nb0, P.dgWs[0], P.dgWn[0], P.dgB[0], 3, nullptr, true,
         P.dgH[0], P.dgHb[0], P.s0, P.out);

    // blocks >= NACT: permanently satisfy their slot and exit
    if (blk >= NACT) {
        asm volatile("s_waitcnt vmcnt(0)" ::: "memory");
        __syncthreads();
        if (tid == 0)
            __hip_atomic_store(&P.slot[blk], SLOT_DONE, __ATOMIC_RELAXED,
                               __HIP_MEMORY_SCOPE_AGENT);
        return;
    }
    BAR(6);

    // ===== NMS (block 0 only; s0/xyz0 plain — fresh lines) =====
    if (blk == 0) {
        for (int jj = tid; jj < N0; jj += BLOCK) u.sc[jj] = P.s0[jj];
        __syncthreads();
        for (int it = 0; it < 3; ++it) {
            float bv = -INFINITY; int bi = 0x7fffffff;
            for (int jj = tid; jj < N0; jj += BLOCK) {
                float v = u.sc[jj];
                if (v > bv) { bv = v; bi = jj; }   // strided ascending: first max kept
            }
            rv[tid] = bv; ri[tid] = bi;
            __syncthreads();
            for (int sft = BLOCK / 2; sft > 0; sft >>= 1) {
                if (tid < sft) {
                    float v2 = rv[tid + sft]; int i2 = ri[tid + sft];
                    if (v2 > rv[tid] || (v2 == rv[tid] && i2 < ri[tid])) {
                        rv[tid] = v2; ri[tid] = i2;
                    }
                }
                __syncthreads();
            }
            int sel = ri[0];
            if (tid == 0) {
                stci(&P.anchorA[it], P.ind0[sel]);
                psel[0] = P.xyz0[sel * 3 + 0];
                psel[1] = P.xyz0[sel * 3 + 1];
                psel[2] = P.xyz0[sel * 3 + 2];
            }
            __syncthreads();
            float px = psel[0], py = psel[1], pz = psel[2];
            for (int jj = tid; jj < N0; jj += BLOCK) {
                float d = fabsf(P.xyz0[jj * 3 + 0] * px + P.xyz0[jj * 3 + 1] * py
                              + P.xyz0[jj * 3 + 2] * pz);
                if (d >= COS_T) u.sc[jj] = NEG_INF;
            }
            __syncthreads();
        }
    }
    BAR(7);

    // ===== stages 1 & 2 (384 blocks x 8 nodes; 1 node/wave) =====
    for (int st = 1; st <= 2; ++st) {
        float* const* xb = (st == 1) ? P.xs1 : P.xs2;
        int* indb = (st == 1) ? P.indb1 : P.indb2;
        int* nbb  = (st == 1) ? P.nbb1  : P.nbb2;
        const int* anc = (st == 1) ? P.anchorA : P.anchorB;
        const int ep = (st == 1) ? 7 : 13;
        const int jb12 = blk * 8;

        topk(P.isc[st - 1], anc, indb, nbb);
        sphere(8, jb12, indb, P.wsS[st], P.bsS[st], xb[0]);
        BAR(ep + 1);
        dgcn(8, jb12, xb[0], nbb, P.dgWs[st], P.dgWn[st], P.dgB[st], 0, xb[1], false, nullptr, nullptr, nullptr, nullptr);
        BAR(ep + 2);
        dgcn(8, jb12, xb[1], nbb, P.dgWs[st], P.dgWn[st], P.dgB[st], 1, xb[2], false, nullptr, nullptr, nullptr, nullptr);
        BAR(ep + 3);
        dgcn(8, jb12, xb[2], nbb, P.dgWs[st], P.dgWn[st], P.dgB[st], 2, xb[3], false, nullptr, nullptr, nullptr, nullptr);
        BAR(ep + 4);
        dgcn(8, jb12, xb[3], nbb, P.dgWs[st], P.dgWn[st], P.dgB[st], 3, nullptr, true,
             P.dgH[st], P.dgHb[st], (st == 1) ? P.sbr : nullptr,
             P.out + N0 + (st - 1) * 3 * N1);
        if (st == 1) {
            BAR(12);
            if (blk < 3) {    // per-branch argmax over sbr (plain, fresh)
                float bv = -INFINITY; int bi = 0x7fffffff;
                for (int m = tid; m < N1; m += BLOCK) {
                    float v = P.sbr[blk * N1 + m];
                    if (v > bv) { bv = v; bi = m; }   // ascending: first max kept
                }
                rv[tid] = bv; ri[tid] = bi;
                __syncthreads();
                for (int sft = BLOCK / 2; sft > 0; sft >>= 1) {
                    if (tid < sft) {
                        float v2 = rv[tid + sft]; int i2 = ri[tid + sft];
                        if (v2 > rv[tid] || (v2 == rv[tid] && i2 < ri[tid])) {
                            rv[tid] = v2; ri[tid] = i2;
                        }
                    }
                    __syncthreads();
                }
                if (tid == 0) stci(&P.anchorB[blk], P.indb1[blk * N1 + ri[0]]);
            }
            BAR(13);
        }
    }
}

extern "C" void kernel_launch(void* const* d_in, const int* in_sizes, int n_in,
                              void* d_out, int out_size, void* d_ws, size_t ws_size,
                              hipStream_t stream) {
    MegaParams hp;
    hp.feat = (const float*)d_in[0];
    hp.xyz  = (const float*)d_in[1];
    hp.wsS[0] = (const float*)d_in[2];  hp.bsS[0] = (const float*)d_in[3];
    hp.wsS[1] = (const float*)d_in[4];  hp.bsS[1] = (const float*)d_in[5];
    hp.wsS[2] = (const float*)d_in[6];  hp.bsS[2] = (const float*)d_in[7];
    hp.dgWs[0] = (const float*)d_in[8];  hp.dgWn[0] = (const float*)d_in[9];
    hp.dgB[0]  = (const float*)d_in[10]; hp.dgH[0]  = (const float*)d_in[11];
    hp.dgHb[0] = (const float*)d_in[12];
    hp.dgWs[1] = (const float*)d_in[13]; hp.dgWn[1] = (const float*)d_in[14];
    hp.dgB[1]  = (const float*)d_in[15]; hp.dgH[1]  = (const float*)d_in[16];
    hp.dgHb[1] = (const float*)d_in[17];
    hp.dgWs[2] = (const float*)d_in[18]; hp.dgWn[2] = (const float*)d_in[19];
    hp.dgB[2]  = (const float*)d_in[20]; hp.dgH[2]  = (const float*)d_in[21];
    hp.dgHb[2] = (const float*)d_in[22];
    const int* edge0 = (const int*)d_in[23];
    hp.nb0  = edge0 + N0 * KNB;
    hp.ind0 = (const int*)d_in[24];
    hp.isc[0] = (const int*)d_in[25];
    hp.isc[1] = (const int*)d_in[26];
    hp.out = (float*)d_out;

    float* f = (float*)d_ws;
    size_t o = 0;
    auto takeF = [&](size_t n) { float* p = f + o; o += n; return p; };

    hp.s0   = takeF(N0);
    hp.sbr  = takeF(3 * N1);
    hp.xyz0 = takeF((size_t)N0 * 3);
    o = (o + 63) & ~(size_t)63;
    hp.anchorA = (int*)takeF(64);
    hp.anchorB = (int*)takeF(64);
    hp.indb1 = (int*)takeF(3 * N1);
    hp.nbb1  = (int*)takeF(3 * N1 * KNB);
    hp.indb2 = (int*)takeF(3 * N1);
    hp.nbb2  = (int*)takeF(3 * N1 * KNB);
    o = (o + 63) & ~(size_t)63;
    hp.slot = (unsigned*)takeF(GRID);
    hp.flag = (unsigned*)takeF(8 * 16);
    unsigned* ctrBase = hp.slot;

    size_t needFast = (o + 4 * (size_t)N0 * C_H + 8 * (size_t)(3 * N1) * C_H) * sizeof(float);
    if (ws_size >= needFast) {
        hp.actCoh = 0;
        for (int i = 0; i < 4; ++i) hp.xs0[i] = takeF((size_t)N0 * C_H);
        for (int i = 0; i < 4; ++i) hp.xs1[i] = takeF((size_t)(3 * N1) * C_H);
        for (int i = 0; i < 4; ++i) hp.xs2[i] = takeF((size_t)(3 * N1) * C_H);
    } else {
        hp.actCoh = 1;
        float* xA = takeF((size_t)N0 * C_H);
        float* xB = takeF((size_t)N0 * C_H);
        for (int i = 0; i < 4; ++i) {
            hp.xs0[i] = (i & 1) ? xB : xA;
            hp.xs1[i] = (i & 1) ? xB : xA;
            hp.xs2[i] = (i & 1) ? xB : xA;
        }
    }

    size_t needTr = (o + (size_t)N_TOTAL * C_IN) * sizeof(float);
    if (ws_size >= needTr) {
        hp.tr = 1;
        hp.featT = takeF((size_t)N_TOTAL * C_IN);
    } else {
        hp.tr = 0;
        hp.featT = nullptr;
    }

    hipMemsetAsync((void*)ctrBase, 0, (GRID + 8 * 16) * sizeof(unsigned), stream);
    mega_kernel<<<dim3(GRID), dim3(BLOCK), 0, stream>>>(hp);
}